// Round 5
// baseline (23420.529 us; speedup 1.0000x reference)
//
#include <hip/hip_runtime.h>
#include <hip/hip_cooperative_groups.h>

// SGRU, skewed-pipeline merged-step MFMA implementation (dtype-agnostic bf16/fp32).
// Pipeline: gates(s,t) at step p=t+2s computes h_new; out(s,t) at p=t+2s+1 computes
// pred = concat(x,h_new)@Wo.T + bo. Grid: blocks 0..255 = gates (4 stacks x 2 Mtiles
// x 32 Ntiles of 32 cols x 3 gates), blocks 256..383 = out (4 stacks x 2 Mtiles x 16
// Ntiles). Stack 3 reuses weight index 2 (faithful source bug). Final log_softmax.
// State: fp32 h single buffer (in-place, same-thread RMW); bf16 h double-buffered by
// t-parity; x quad-buffered by t&3 (written by out(s-1,t), read +1/+2 steps).
//
// R1: one-time pre-conversion of weights + xb (time-major) to bf16 workspace (mode 2).
// R2: K-loop software pipeline — LDS double-buffered, ONE barrier per K-chunk, global
//     loads for chunk i+1 issued during compute[i]. (10.19 ms verified)
// R3: direct-A/M=64 variant REGRESSED 2.7x (strided A loads, 1 wave/SIMD) — reverted.
// R4: hoisted-base variant REGRESSED 1.65x (bases live across K-loop -> register
//     pressure/spill under launch_bounds(256,2)) — reverted. Inner loop must keep
//     R2's recompute-per-chunk pattern.
// R5: R2 body EXACTLY; step loop moved into ONE persistent cooperative kernel with
//     grid.sync() between steps (removes 263 launch boundaries). Host falls back to
//     per-step launches if cooperative launch is unavailable.

namespace cg = cooperative_groups;

typedef unsigned short u16;
typedef __attribute__((ext_vector_type(8))) short bf16x8;
typedef __attribute__((ext_vector_type(4))) float f32x4;

#define T_LEN 256
#define B_SZ  256
#define INSZ  512
#define HD    1024
#define HPAR  (4 * B_SZ * HD)     // bf16 h elems per t-parity
#define XSLOT (4 * B_SZ * INSZ)   // x elems per t&3 slot
#define PRED_N ((size_t)B_SZ * T_LEN * INSZ)

// workspace layout (bytes)
#define OFF_HF   ((size_t)0)                    // 4 MB fp32 h
#define OFF_HBF  ((size_t)4 << 20)              // 4 MB bf16 h (2 parities)
#define OFF_XQ   ((size_t)8 << 20)              // 4 MB bf16 x quad-buffer
#define OFF_FLAG ((size_t)12 << 20)             // dtype flag
#define OFF_WXB  ((size_t)13 << 20)             // 3*3072*512  bf16 =  9,437,184 B
#define OFF_WHB  (OFF_WXB + (size_t)9437184)    // 3*3072*1024 bf16 = 18,874,368 B
#define OFF_WOB  (OFF_WHB + (size_t)18874368)   // 3*512*1536  bf16 =  4,718,592 B
#define WS_NEED_W (OFF_WOB + (size_t)4718592)   // = 46,661,632
#define OFF_XT   ((size_t)48 << 20)             // [T][B][512] bf16 = 33,554,432 B
#define WS_NEED_X (OFF_XT + (size_t)33554432)   // = 83,886,080

__device__ __forceinline__ float b2f(u16 u) {
    union { unsigned int i; float f; } v; v.i = ((unsigned int)u) << 16; return v.f;
}
__device__ __forceinline__ u16 f2b(float f) {
    union { float f; unsigned int i; } v; v.f = f;
    unsigned int u = v.i;
    return (u16)((u + 0x7FFFu + ((u >> 16) & 1u)) >> 16);
}
// load 8 consecutive elements at element-offset off, return packed bf16 bits
__device__ __forceinline__ uint4 ld8(const void* base, size_t off, int f32) {
    if (!f32) return *(const uint4*)((const u16*)base + off);
    const float* f = (const float*)base + off;
    float4 a = *(const float4*)f;
    float4 b = *(const float4*)(f + 4);
    union { u16 o[8]; uint4 v; } u;
    u.o[0]=f2b(a.x); u.o[1]=f2b(a.y); u.o[2]=f2b(a.z); u.o[3]=f2b(a.w);
    u.o[4]=f2b(b.x); u.o[5]=f2b(b.y); u.o[6]=f2b(b.z); u.o[7]=f2b(b.w);
    return u.v;
}
__device__ __forceinline__ float ldf(const void* base, size_t i, int f32) {
    return f32 ? ((const float*)base)[i] : b2f(((const u16*)base)[i]);
}

// ---------------- dtype probe ----------------
__global__ void sgru_probe(const void* Wx, int* flag)
{
    const int l = threadIdx.x;
    const u16* w = (const u16*)Wx;
    int cnt = 0;
    for (int i = l; i < 1024; i += 64) {
        float v = b2f(w[i]);
        if (!(fabsf(v) <= 1.0f)) cnt++;   // counts big values and NaN
    }
#pragma unroll
    for (int off = 32; off >= 1; off >>= 1) cnt += __shfl_xor(cnt, off, 64);
    if (l == 0) *flag = (cnt > 10) ? 1 : 0;
}

// ---------------- init: h0 -> hf + both bf16 parities; zero xq ----------------
__global__ __launch_bounds__(256)
void sgru_init(const void* h0, float* __restrict__ hf, u16* __restrict__ hbf,
               u16* __restrict__ xq, const int* flag)
{
    const int f32 = *flag;
    const int idx = blockIdx.x * 256 + threadIdx.x;  // < 1<<20 == s*262144 + b*1024 + j
    const int s = idx >> 18;
    const int b = (idx >> 10) & 255;
    const int j = idx & 1023;
    const float v = ldf(h0, (size_t)b * 4096 + s * 1024 + j, f32);
    const u16 hv = f2b(v);
    hf[idx] = v;
    hbf[idx] = hv; hbf[idx + HPAR] = hv;
    xq[idx] = 0; xq[idx + (1 << 20)] = 0;   // 2^21 u16 total = all 4 slots
}

// ---------------- one-time dtype conversion: linear copy/convert to bf16 ----------------
__global__ __launch_bounds__(256)
void sgru_cvt(const void* __restrict__ src, u16* __restrict__ dst, const int* __restrict__ flag)
{
    const int f32 = *flag;
    const size_t off = ((size_t)blockIdx.x * 256 + threadIdx.x) * 8;
    *(uint4*)(dst + off) = ld8(src, off, f32);
}

// ---------------- one-time xb -> time-major bf16 [T][B][512] ----------------
__global__ __launch_bounds__(256)
void sgru_cvtx(const void* __restrict__ xb, u16* __restrict__ xt, const int* __restrict__ flag)
{
    const int f32 = *flag;
    const size_t g = (size_t)blockIdx.x * 256 + threadIdx.x;   // 4,194,304 threads
    const int c = (int)(g & 63) * 8;
    const int b = (int)((g >> 6) & 255);
    const int t = (int)(g >> 14);
    uint4 v = ld8(xb, ((size_t)b * T_LEN + t) * INSZ + c, f32);
    *(uint4*)&xt[((size_t)t * B_SZ + b) * INSZ + c] = v;
}

// ---------------- one step of the skewed pipeline (R2 body, verbatim) ----------------
__device__ __forceinline__
void step_body(int p, u16* Ax, u16* Bw,
               const void* __restrict__ xb,
               const void* __restrict__ Wx, const void* __restrict__ bx,
               const void* __restrict__ Wh, const void* __restrict__ bh,
               const void* __restrict__ Wo, const void* __restrict__ bo,
               float* __restrict__ hf, u16* __restrict__ hbf,
               u16* __restrict__ xq, void* __restrict__ dout,
               const u16* __restrict__ Wxb, const u16* __restrict__ Whb,
               const u16* __restrict__ Wob, const u16* __restrict__ xt,
               int mode, int f32)
{
    const int tid = threadIdx.x;
    const int w = tid >> 6, l = tid & 63;
    const int quad = l >> 4, m16 = l & 15;
    const int bid = blockIdx.x;

    if (bid < 256) {
        // ---------- gates role ----------
        const int s = bid >> 6, r6 = bid & 63, mt = r6 >> 5, nt = r6 & 31;
        const int t = p - 2 * s;
        if (t < 0 || t >= T_LEN) return;
        const int widx = (s == 3) ? 2 : s;
        const int b0 = mt * 128, n0 = nt * 32;

        float* __restrict__ hfs = hf + (size_t)s * (B_SZ * HD);
        const u16* __restrict__ hbin  = hbf + (size_t)((t & 1) ^ 1) * HPAR + (size_t)s * (B_SZ * HD);
        u16* __restrict__ hbout       = hbf + (size_t)(t & 1) * HPAR + (size_t)s * (B_SZ * HD);
        const u16* __restrict__ xin   = xq + (size_t)(t & 3) * XSLOT + (size_t)s * (B_SZ * INSZ);
        const size_t WxO = (size_t)widx * 3072 * 512;
        const size_t WhO = (size_t)widx * 3072 * 1024;

        f32x4 aU[2][2], aR[2][2], aXN[2][2], aHN[2][2];
        const f32x4 z = {0.f, 0.f, 0.f, 0.f};
#pragma unroll
        for (int i = 0; i < 2; ++i)
#pragma unroll
            for (int jn = 0; jn < 2; ++jn) { aU[i][jn] = z; aR[i][jn] = z; aXN[i][jn] = z; aHN[i][jn] = z; }

        uint4 aV[4], wV[3];
        auto load_gates = [&](int kcL) {
            const int k0 = kcL * 64;
            const bool xp = (k0 < 512);
#pragma unroll
            for (int it = 0; it < 4; ++it) {
                int i = tid + it * 256;
                int row = i >> 3, col = (i & 7) * 8;
                uint4 v;
                if (xp) {
                    if (s == 0) {
                        if (mode == 2) v = *(const uint4*)&xt[((size_t)t * B_SZ + b0 + row) * INSZ + k0 + col];
                        else           v = ld8(xb, ((size_t)(b0 + row) * T_LEN + t) * INSZ + k0 + col, f32);
                    } else {
                        v = *(const uint4*)&xin[(size_t)(b0 + row) * INSZ + k0 + col];
                    }
                } else {
                    v = *(const uint4*)&hbin[(size_t)(b0 + row) * HD + (k0 - 512 + col)];
                }
                aV[it] = v;
            }
#pragma unroll
            for (int it = 0; it < 3; ++it) {
                int i = tid + it * 256;
                int r = i >> 3, col = (i & 7) * 8;
                int g = r >> 5, rr = r & 31;
                int wrow = g * HD + n0 + rr;
                uint4 v;
                if (mode) {
                    v = xp ? *(const uint4*)&Wxb[(size_t)widx * 1572864 + (size_t)wrow * 512 + k0 + col]
                           : *(const uint4*)&Whb[(size_t)widx * 3145728 + (size_t)wrow * 1024 + (k0 - 512) + col];
                } else {
                    v = xp ? ld8(Wx, WxO + (size_t)wrow * 512 + k0 + col, f32)
                           : ld8(Wh, WhO + (size_t)wrow * 1024 + (k0 - 512) + col, f32);
                }
                wV[it] = v;
            }
        };

        load_gates(0);
        for (int kc = 0; kc < 24; ++kc) {
            const int k0 = kc * 64;
            const bool xp = (k0 < 512);
            u16* __restrict__ axb = Ax + (kc & 1) * (128 * 72);
            u16* __restrict__ bwb = Bw + (kc & 1) * (96 * 72);
            // write phase: prefetched regs -> LDS buf[kc&1]
#pragma unroll
            for (int it = 0; it < 4; ++it) {
                int i = tid + it * 256;
                int row = i >> 3, col = (i & 7) * 8;
                *(uint4*)&axb[row * 72 + col] = aV[it];
            }
#pragma unroll
            for (int it = 0; it < 3; ++it) {
                int i = tid + it * 256;
                int r = i >> 3, col = (i & 7) * 8;
                *(uint4*)&bwb[r * 72 + col] = wV[it];
            }
            __syncthreads();
            // issue next chunk's global loads (hide latency under MFMA phase)
            if (kc < 23) load_gates(kc + 1);
            // compute phase on buf[kc&1]
#pragma unroll
            for (int kh = 0; kh < 2; ++kh) {
                const int kf = kh * 32 + quad * 8;
                bf16x8 a0 = *(const bf16x8*)&axb[(w * 32 +      m16) * 72 + kf];
                bf16x8 a1 = *(const bf16x8*)&axb[(w * 32 + 16 + m16) * 72 + kf];
#pragma unroll
                for (int ntl = 0; ntl < 2; ++ntl) {
                    bf16x8 bu = *(const bf16x8*)&bwb[(     ntl * 16 + m16) * 72 + kf];
                    bf16x8 br = *(const bf16x8*)&bwb[(32 + ntl * 16 + m16) * 72 + kf];
                    bf16x8 bn = *(const bf16x8*)&bwb[(64 + ntl * 16 + m16) * 72 + kf];
                    aU[0][ntl] = __builtin_amdgcn_mfma_f32_16x16x32_bf16(a0, bu, aU[0][ntl], 0, 0, 0);
                    aU[1][ntl] = __builtin_amdgcn_mfma_f32_16x16x32_bf16(a1, bu, aU[1][ntl], 0, 0, 0);
                    aR[0][ntl] = __builtin_amdgcn_mfma_f32_16x16x32_bf16(a0, br, aR[0][ntl], 0, 0, 0);
                    aR[1][ntl] = __builtin_amdgcn_mfma_f32_16x16x32_bf16(a1, br, aR[1][ntl], 0, 0, 0);
                    if (xp) {
                        aXN[0][ntl] = __builtin_amdgcn_mfma_f32_16x16x32_bf16(a0, bn, aXN[0][ntl], 0, 0, 0);
                        aXN[1][ntl] = __builtin_amdgcn_mfma_f32_16x16x32_bf16(a1, bn, aXN[1][ntl], 0, 0, 0);
                    } else {
                        aHN[0][ntl] = __builtin_amdgcn_mfma_f32_16x16x32_bf16(a0, bn, aHN[0][ntl], 0, 0, 0);
                        aHN[1][ntl] = __builtin_amdgcn_mfma_f32_16x16x32_bf16(a1, bn, aHN[1][ntl], 0, 0, 0);
                    }
                }
            }
        }

        // epilogue: gate math + in-place fp32 h RMW + bf16 h + final hds
#pragma unroll
        for (int ntl = 0; ntl < 2; ++ntl) {
            const int j = n0 + ntl * 16 + m16;
            const size_t bb = (size_t)widx * 3072;
            const float bxu = ldf(bx, bb + j, f32),        bhu = ldf(bh, bb + j, f32);
            const float bxr = ldf(bx, bb + 1024 + j, f32), bhr = ldf(bh, bb + 1024 + j, f32);
            const float bxn = ldf(bx, bb + 2048 + j, f32), bhn = ldf(bh, bb + 2048 + j, f32);
#pragma unroll
            for (int mi = 0; mi < 2; ++mi) {
#pragma unroll
                for (int q = 0; q < 4; ++q) {
                    const int brow = b0 + w * 32 + mi * 16 + quad * 4 + q;
                    float su = aU[mi][ntl][q] + bxu + bhu;
                    float sr = aR[mi][ntl][q] + bxr + bhr;
                    float ug = 1.f / (1.f + __expf(-su));
                    float rg = 1.f / (1.f + __expf(-sr));
                    float ng = tanhf((aXN[mi][ntl][q] + bxn) + rg * (aHN[mi][ntl][q] + bhn));
                    float hold = hfs[(size_t)brow * HD + j];
                    float hnew = ug * hold + (1.f - ug) * ng;
                    hfs[(size_t)brow * HD + j] = hnew;
                    u16 hb = f2b(hnew);
                    hbout[(size_t)brow * HD + j] = hb;
                    if (t == T_LEN - 1) {
                        size_t off = PRED_N + (size_t)brow * 4096 + s * 1024 + j;
                        if (f32) ((float*)dout)[off] = hnew;
                        else     ((u16*)dout)[off]   = hb;
                    }
                }
            }
        }
    } else {
        // ---------- out role ----------
        const int ob = bid - 256;
        const int s = ob >> 5, r5 = ob & 31, mt = r5 >> 4, nt = r5 & 15;
        const int t = p - 1 - 2 * s;
        if (t < 0 || t >= T_LEN) return;
        const int widx = (s == 3) ? 2 : s;
        const int b0 = mt * 128, n0 = nt * 32;

        const u16* __restrict__ hbn = hbf + (size_t)(t & 1) * HPAR + (size_t)s * (B_SZ * HD);
        const u16* __restrict__ xin = xq + (size_t)(t & 3) * XSLOT + (size_t)s * (B_SZ * INSZ);
        u16* __restrict__ xout      = xq + (size_t)(t & 3) * XSLOT + (size_t)(s + 1) * (B_SZ * INSZ);
        const size_t WoO = (size_t)widx * 512 * 1536;

        f32x4 acc[2][2];
        const f32x4 z = {0.f, 0.f, 0.f, 0.f};
#pragma unroll
        for (int i = 0; i < 2; ++i) { acc[i][0] = z; acc[i][1] = z; }

        uint4 aV[4], wV;
        auto load_out = [&](int kcL) {
            const int k0 = kcL * 64;
            const bool xp = (k0 < 512);
#pragma unroll
            for (int it = 0; it < 4; ++it) {
                int i = tid + it * 256;
                int row = i >> 3, col = (i & 7) * 8;
                uint4 v;
                if (xp) {
                    if (s == 0) {
                        if (mode == 2) v = *(const uint4*)&xt[((size_t)t * B_SZ + b0 + row) * INSZ + k0 + col];
                        else           v = ld8(xb, ((size_t)(b0 + row) * T_LEN + t) * INSZ + k0 + col, f32);
                    } else {
                        v = *(const uint4*)&xin[(size_t)(b0 + row) * INSZ + k0 + col];
                    }
                } else {
                    v = *(const uint4*)&hbn[(size_t)(b0 + row) * HD + (k0 - 512 + col)];
                }
                aV[it] = v;
            }
            {
                int r = tid >> 3, col = (tid & 7) * 8;
                if (mode) wV = *(const uint4*)&Wob[(size_t)widx * 786432 + (size_t)(n0 + r) * 1536 + k0 + col];
                else      wV = ld8(Wo, WoO + (size_t)(n0 + r) * 1536 + k0 + col, f32);
            }
        };

        load_out(0);
        for (int kc = 0; kc < 24; ++kc) {
            u16* __restrict__ axb = Ax + (kc & 1) * (128 * 72);
            u16* __restrict__ bwb = Bw + (kc & 1) * (96 * 72);
#pragma unroll
            for (int it = 0; it < 4; ++it) {
                int i = tid + it * 256;
                int row = i >> 3, col = (i & 7) * 8;
                *(uint4*)&axb[row * 72 + col] = aV[it];
            }
            {
                int r = tid >> 3, col = (tid & 7) * 8;
                *(uint4*)&bwb[r * 72 + col] = wV;
            }
            __syncthreads();
            if (kc < 23) load_out(kc + 1);
#pragma unroll
            for (int kh = 0; kh < 2; ++kh) {
                const int kf = kh * 32 + quad * 8;
                bf16x8 a0 = *(const bf16x8*)&axb[(w * 32 +      m16) * 72 + kf];
                bf16x8 a1 = *(const bf16x8*)&axb[(w * 32 + 16 + m16) * 72 + kf];
#pragma unroll
                for (int ntl = 0; ntl < 2; ++ntl) {
                    bf16x8 bf = *(const bf16x8*)&bwb[(ntl * 16 + m16) * 72 + kf];
                    acc[0][ntl] = __builtin_amdgcn_mfma_f32_16x16x32_bf16(a0, bf, acc[0][ntl], 0, 0, 0);
                    acc[1][ntl] = __builtin_amdgcn_mfma_f32_16x16x32_bf16(a1, bf, acc[1][ntl], 0, 0, 0);
                }
            }
        }

#pragma unroll
        for (int ntl = 0; ntl < 2; ++ntl) {
            const int j = n0 + ntl * 16 + m16;
            const float bov = ldf(bo, (size_t)widx * 512 + j, f32);
#pragma unroll
            for (int mi = 0; mi < 2; ++mi) {
#pragma unroll
                for (int q = 0; q < 4; ++q) {
                    const int brow = b0 + w * 32 + mi * 16 + quad * 4 + q;
                    float o = acc[mi][ntl][q] + bov;
                    if (s < 3) {
                        xout[(size_t)brow * INSZ + j] = f2b(o);
                    } else {
                        size_t off = ((size_t)brow * T_LEN + t) * INSZ + j;
                        if (f32) ((float*)dout)[off] = o;
                        else     ((u16*)dout)[off]   = f2b(o);
                    }
                }
            }
        }
    }
}

// ---------------- per-step kernel (fallback path) ----------------
__global__ __launch_bounds__(256, 2)
void sgru_step(int p,
               const void* __restrict__ xb, const void* __restrict__ Wx,
               const void* __restrict__ bx, const void* __restrict__ Wh,
               const void* __restrict__ bh, const void* __restrict__ Wo,
               const void* __restrict__ bo,
               float* __restrict__ hf, u16* __restrict__ hbf,
               u16* __restrict__ xq, void* __restrict__ dout,
               const int* __restrict__ flag,
               const u16* __restrict__ Wxb, const u16* __restrict__ Whb,
               const u16* __restrict__ Wob, const u16* __restrict__ xt,
               int mode)
{
    __shared__ u16 Ax[2 * 128 * 72];
    __shared__ u16 Bw[2 * 96 * 72];
    const int f32 = *flag;
    step_body(p, Ax, Bw, xb, Wx, bx, Wh, bh, Wo, bo,
              hf, hbf, xq, dout, Wxb, Whb, Wob, xt, mode, f32);
}

// ---------------- persistent cooperative kernel: all steps, grid.sync between ----------------
__global__ __launch_bounds__(256, 2)
void sgru_steps_coop(int np,
               const void* __restrict__ xb, const void* __restrict__ Wx,
               const void* __restrict__ bx, const void* __restrict__ Wh,
               const void* __restrict__ bh, const void* __restrict__ Wo,
               const void* __restrict__ bo,
               float* __restrict__ hf, u16* __restrict__ hbf,
               u16* __restrict__ xq, void* __restrict__ dout,
               const int* __restrict__ flag,
               const u16* __restrict__ Wxb, const u16* __restrict__ Whb,
               const u16* __restrict__ Wob, const u16* __restrict__ xt,
               int mode)
{
    __shared__ u16 Ax[2 * 128 * 72];
    __shared__ u16 Bw[2 * 96 * 72];
    const int f32 = *flag;
    cg::grid_group grid = cg::this_grid();
    for (int p = 0; p < np; ++p) {
        step_body(p, Ax, Bw, xb, Wx, bx, Wh, bh, Wo, bo,
                  hf, hbf, xq, dout, Wxb, Whb, Wob, xt, mode, f32);
        grid.sync();
    }
}

// ---------------- batched log_softmax over 512-wide rows, in place ----------------
__global__ __launch_bounds__(256)
void sgru_lsm(void* __restrict__ preds, const int* flag)
{
    const int f32 = *flag;
    const int w = threadIdx.x >> 6, l = threadIdx.x & 63;
    const size_t row = (size_t)blockIdx.x * 4 + w;
    float x[8];
    if (f32) {
        float* p = (float*)preds + row * 512 + (size_t)l * 8;
        float4 a = *(const float4*)p, b = *(const float4*)(p + 4);
        x[0]=a.x; x[1]=a.y; x[2]=a.z; x[3]=a.w; x[4]=b.x; x[5]=b.y; x[6]=b.z; x[7]=b.w;
    } else {
        const u16* p = (const u16*)preds + row * 512 + (size_t)l * 8;
        uint4 v = *(const uint4*)p;
        const u16* pv = (const u16*)&v;
#pragma unroll
        for (int i = 0; i < 8; ++i) x[i] = b2f(pv[i]);
    }
    float m = x[0];
#pragma unroll
    for (int i = 1; i < 8; ++i) m = fmaxf(m, x[i]);
#pragma unroll
    for (int off = 32; off >= 1; off >>= 1) m = fmaxf(m, __shfl_xor(m, off, 64));
    float sum = 0.f;
#pragma unroll
    for (int i = 0; i < 8; ++i) sum += __expf(x[i] - m);
#pragma unroll
    for (int off = 32; off >= 1; off >>= 1) sum += __shfl_xor(sum, off, 64);
    const float ls = m + logf(sum);
    if (f32) {
        float* p = (float*)preds + row * 512 + (size_t)l * 8;
        float4 a, b;
        a.x=x[0]-ls; a.y=x[1]-ls; a.z=x[2]-ls; a.w=x[3]-ls;
        b.x=x[4]-ls; b.y=x[5]-ls; b.z=x[6]-ls; b.w=x[7]-ls;
        *(float4*)p = a; *(float4*)(p + 4) = b;
    } else {
        u16* p = (u16*)preds + row * 512 + (size_t)l * 8;
        union { u16 o[8]; uint4 v; } u;
#pragma unroll
        for (int i = 0; i < 8; ++i) u.o[i] = f2b(x[i] - ls);
        *(uint4*)p = u.v;
    }
}

extern "C" void kernel_launch(void* const* d_in, const int* in_sizes, int n_in,
                              void* d_out, int out_size, void* d_ws, size_t ws_size,
                              hipStream_t stream) {
    const void* xb = d_in[0];
    const void* h0 = d_in[1];
    const void* Wx = d_in[2];
    const void* bx = d_in[3];
    const void* Wh = d_in[4];
    const void* bh = d_in[5];
    const void* Wo = d_in[6];
    const void* bo = d_in[7];
    (void)in_sizes; (void)n_in; (void)out_size;

    char* ws = (char*)d_ws;
    float* hf  = (float*)(ws + OFF_HF);     // [4][256][1024] f32, in-place (4 MB)
    u16*   hbf = (u16*)(ws + OFF_HBF);      // [2][4][256][1024] bf16 (4 MB)
    u16*   xq  = (u16*)(ws + OFF_XQ);       // [4][4][256][512]  bf16 (4 MB)
    int*   flag = (int*)(ws + OFF_FLAG);    // dtype flag
    u16*   Wxb = (u16*)(ws + OFF_WXB);      // [3][3072][512]  bf16
    u16*   Whb = (u16*)(ws + OFF_WHB);      // [3][3072][1024] bf16
    u16*   Wob = (u16*)(ws + OFF_WOB);      // [3][512][1536]  bf16
    u16*   xt  = (u16*)(ws + OFF_XT);       // [256][256][512] bf16, time-major

    const int mode = (ws_size >= WS_NEED_X) ? 2 : (ws_size >= WS_NEED_W ? 1 : 0);

    sgru_probe<<<1, 64, 0, stream>>>(Wx, flag);
    sgru_init<<<4096, 256, 0, stream>>>(h0, hf, hbf, xq, flag);
    if (mode >= 1) {
        sgru_cvt<<<2304, 256, 0, stream>>>(Wx, Wxb, flag);  // 4,718,592 elems
        sgru_cvt<<<4608, 256, 0, stream>>>(Wh, Whb, flag);  // 9,437,184 elems
        sgru_cvt<<<1152, 256, 0, stream>>>(Wo, Wob, flag);  // 2,359,296 elems
    }
    if (mode == 2) {
        sgru_cvtx<<<16384, 256, 0, stream>>>(xb, xt, flag); // 33,554,432 elems
    }

    // ---- step pipeline: persistent cooperative kernel, fallback to per-step ----
    int np = T_LEN + 7;   // 263 steps: last out at p = 255 + 1 + 6
    int imode = mode;
    bool coop_done = false;
    int coop_attr = 0;
    {
        int dev = 0;
        if (hipGetDevice(&dev) == hipSuccess)
            (void)hipDeviceGetAttribute(&coop_attr, hipDeviceAttributeCooperativeLaunch, dev);
    }
    if (coop_attr) {
        void* kargs[] = { &np, (void*)&xb, (void*)&Wx, (void*)&bx, (void*)&Wh,
                          (void*)&bh, (void*)&Wo, (void*)&bo, (void*)&hf, (void*)&hbf,
                          (void*)&xq, (void*)&d_out, (void*)&flag, (void*)&Wxb,
                          (void*)&Whb, (void*)&Wob, (void*)&xt, &imode };
        hipError_t e = hipLaunchCooperativeKernel(reinterpret_cast<void*>(sgru_steps_coop),
                                                  dim3(384), dim3(256), kargs, 0, stream);
        if (e == hipSuccess) coop_done = true;
        else (void)hipGetLastError();   // clear sticky error, fall back
    }
    if (!coop_done) {
        for (int p = 0; p < np; ++p) {
            sgru_step<<<384, 256, 0, stream>>>(p, xb, Wx, bx, Wh, bh, Wo, bo,
                                               hf, hbf, xq, d_out, flag,
                                               Wxb, Whb, Wob, xt, mode);
        }
    }
    sgru_lsm<<<16384, 256, 0, stream>>>(d_out, flag);
}

// Round 6
// 6828.881 us; speedup vs baseline: 3.4296x; 3.4296x over previous
//
#include <hip/hip_runtime.h>

// SGRU, skewed-pipeline merged-step MFMA implementation (dtype-agnostic bf16/fp32).
// Pipeline: gates(s,t) at step p=t+2s computes h_new; out(s,t) at p=t+2s+1 computes
// pred = concat(x,h_new)@Wo.T + bo. One launch per step (263 steps).
// Stack 3 reuses weight index 2 (faithful source bug). Final: log_softmax in place.
// State: fp32 h single buffer (in-place, same-thread RMW); bf16 h double-buffered by
// t-parity; x quad-buffered by t&3 (written by out(s-1,t), read +1/+2 steps).
//
// R1: one-time pre-conversion of weights + xb (time-major) to bf16 workspace (mode 2).
// R2: K-loop software pipeline — LDS double-buffered, ONE barrier per K-chunk, global
//     loads for chunk i+1 issued during compute[i]. (10.19 ms verified)
// R3: direct-A/M=64-per-wave variant REGRESSED 2.7x (strided A loads, 1 wave/SIMD).
// R4: hoisted-base variant REGRESSED 1.65x (long live ranges -> spill). Keep
//     recompute-per-chunk staging lambdas.
// R5: persistent cooperative kernel REGRESSED 2.3x (grid.sync ~50us/step at 384
//     blocks). Counters: MfmaUtil 4.9%, VALUBusy 5.8%, Occupancy 18.7% -> latency/
//     occupancy-bound; 384 blocks = non-uniform 1-2 blocks/CU.
// R6: occupancy attack — 64-row M-tiles: gates 4s x 4mt x 32nt = 512 blocks, out
//     4s x 4mt x 16nt = 256 blocks; 768 blocks = EXACTLY 3 blocks/CU, 12 waves/CU
//     (2x). LDS 45KB/block, per-wave 16 rows (acc halves). Same staging pattern,
//     same barrier schedule as R2.

typedef unsigned short u16;
typedef __attribute__((ext_vector_type(8))) short bf16x8;
typedef __attribute__((ext_vector_type(4))) float f32x4;

#define T_LEN 256
#define B_SZ  256
#define INSZ  512
#define HD    1024
#define HPAR  (4 * B_SZ * HD)     // bf16 h elems per t-parity
#define XSLOT (4 * B_SZ * INSZ)   // x elems per t&3 slot
#define PRED_N ((size_t)B_SZ * T_LEN * INSZ)

// workspace layout (bytes)
#define OFF_HF   ((size_t)0)                    // 4 MB fp32 h
#define OFF_HBF  ((size_t)4 << 20)              // 4 MB bf16 h (2 parities)
#define OFF_XQ   ((size_t)8 << 20)              // 4 MB bf16 x quad-buffer
#define OFF_FLAG ((size_t)12 << 20)             // dtype flag
#define OFF_WXB  ((size_t)13 << 20)             // 3*3072*512  bf16 =  9,437,184 B
#define OFF_WHB  (OFF_WXB + (size_t)9437184)    // 3*3072*1024 bf16 = 18,874,368 B
#define OFF_WOB  (OFF_WHB + (size_t)18874368)   // 3*512*1536  bf16 =  4,718,592 B
#define WS_NEED_W (OFF_WOB + (size_t)4718592)   // = 46,661,632
#define OFF_XT   ((size_t)48 << 20)             // [T][B][512] bf16 = 33,554,432 B
#define WS_NEED_X (OFF_XT + (size_t)33554432)   // = 83,886,080

__device__ __forceinline__ float b2f(u16 u) {
    union { unsigned int i; float f; } v; v.i = ((unsigned int)u) << 16; return v.f;
}
__device__ __forceinline__ u16 f2b(float f) {
    union { float f; unsigned int i; } v; v.f = f;
    unsigned int u = v.i;
    return (u16)((u + 0x7FFFu + ((u >> 16) & 1u)) >> 16);
}
// load 8 consecutive elements at element-offset off, return packed bf16 bits
__device__ __forceinline__ uint4 ld8(const void* base, size_t off, int f32) {
    if (!f32) return *(const uint4*)((const u16*)base + off);
    const float* f = (const float*)base + off;
    float4 a = *(const float4*)f;
    float4 b = *(const float4*)(f + 4);
    union { u16 o[8]; uint4 v; } u;
    u.o[0]=f2b(a.x); u.o[1]=f2b(a.y); u.o[2]=f2b(a.z); u.o[3]=f2b(a.w);
    u.o[4]=f2b(b.x); u.o[5]=f2b(b.y); u.o[6]=f2b(b.z); u.o[7]=f2b(b.w);
    return u.v;
}
__device__ __forceinline__ float ldf(const void* base, size_t i, int f32) {
    return f32 ? ((const float*)base)[i] : b2f(((const u16*)base)[i]);
}

// ---------------- dtype probe ----------------
__global__ void sgru_probe(const void* Wx, int* flag)
{
    const int l = threadIdx.x;
    const u16* w = (const u16*)Wx;
    int cnt = 0;
    for (int i = l; i < 1024; i += 64) {
        float v = b2f(w[i]);
        if (!(fabsf(v) <= 1.0f)) cnt++;   // counts big values and NaN
    }
#pragma unroll
    for (int off = 32; off >= 1; off >>= 1) cnt += __shfl_xor(cnt, off, 64);
    if (l == 0) *flag = (cnt > 10) ? 1 : 0;
}

// ---------------- init: h0 -> hf + both bf16 parities; zero xq ----------------
__global__ __launch_bounds__(256)
void sgru_init(const void* h0, float* __restrict__ hf, u16* __restrict__ hbf,
               u16* __restrict__ xq, const int* flag)
{
    const int f32 = *flag;
    const int idx = blockIdx.x * 256 + threadIdx.x;  // < 1<<20 == s*262144 + b*1024 + j
    const int s = idx >> 18;
    const int b = (idx >> 10) & 255;
    const int j = idx & 1023;
    const float v = ldf(h0, (size_t)b * 4096 + s * 1024 + j, f32);
    const u16 hv = f2b(v);
    hf[idx] = v;
    hbf[idx] = hv; hbf[idx + HPAR] = hv;
    xq[idx] = 0; xq[idx + (1 << 20)] = 0;   // 2^21 u16 total = all 4 slots
}

// ---------------- one-time dtype conversion: linear copy/convert to bf16 ----------------
__global__ __launch_bounds__(256)
void sgru_cvt(const void* __restrict__ src, u16* __restrict__ dst, const int* __restrict__ flag)
{
    const int f32 = *flag;
    const size_t off = ((size_t)blockIdx.x * 256 + threadIdx.x) * 8;
    *(uint4*)(dst + off) = ld8(src, off, f32);
}

// ---------------- one-time xb -> time-major bf16 [T][B][512] ----------------
__global__ __launch_bounds__(256)
void sgru_cvtx(const void* __restrict__ xb, u16* __restrict__ xt, const int* __restrict__ flag)
{
    const int f32 = *flag;
    const size_t g = (size_t)blockIdx.x * 256 + threadIdx.x;   // 4,194,304 threads
    const int c = (int)(g & 63) * 8;
    const int b = (int)((g >> 6) & 255);
    const int t = (int)(g >> 14);
    uint4 v = ld8(xb, ((size_t)b * T_LEN + t) * INSZ + c, f32);
    *(uint4*)&xt[((size_t)t * B_SZ + b) * INSZ + c] = v;
}

// ---------------- merged per-step kernel ----------------
__global__ __launch_bounds__(256, 3)
void sgru_step(int p,
               const void* __restrict__ xb, const void* __restrict__ Wx,
               const void* __restrict__ bx, const void* __restrict__ Wh,
               const void* __restrict__ bh, const void* __restrict__ Wo,
               const void* __restrict__ bo,
               float* __restrict__ hf, u16* __restrict__ hbf,
               u16* __restrict__ xq, void* __restrict__ dout,
               const int* __restrict__ flag,
               const u16* __restrict__ Wxb, const u16* __restrict__ Whb,
               const u16* __restrict__ Wob, const u16* __restrict__ xt,
               int mode)
{
    const int tid = threadIdx.x;
    const int w = tid >> 6, l = tid & 63;
    const int quad = l >> 4, m16 = l & 15;
    const int bid = blockIdx.x;
    const int f32 = *flag;

    // double-buffered tiles: one barrier per K-chunk (45 KB -> 3 blocks/CU)
    __shared__ u16 Ax[2 * 64 * 72];    // A tile: 64 rows x 64 K, stride 72
    __shared__ u16 Bw[2 * 96 * 72];    // gates: 96 weight rows; out: 32 rows

    if (bid < 512) {
        // ---------- gates role: 64 rows x 32 cols x 3 gates ----------
        const int s = bid >> 7, r7 = bid & 127, mt = r7 >> 5, nt = r7 & 31;
        const int t = p - 2 * s;
        if (t < 0 || t >= T_LEN) return;
        const int widx = (s == 3) ? 2 : s;
        const int b0 = mt * 64, n0 = nt * 32;

        float* __restrict__ hfs = hf + (size_t)s * (B_SZ * HD);
        const u16* __restrict__ hbin  = hbf + (size_t)((t & 1) ^ 1) * HPAR + (size_t)s * (B_SZ * HD);
        u16* __restrict__ hbout       = hbf + (size_t)(t & 1) * HPAR + (size_t)s * (B_SZ * HD);
        const u16* __restrict__ xin   = xq + (size_t)(t & 3) * XSLOT + (size_t)s * (B_SZ * INSZ);
        const size_t WxO = (size_t)widx * 3072 * 512;
        const size_t WhO = (size_t)widx * 3072 * 1024;

        f32x4 aU[2], aR[2], aXN[2], aHN[2];   // [ntl]
        const f32x4 z = {0.f, 0.f, 0.f, 0.f};
#pragma unroll
        for (int jn = 0; jn < 2; ++jn) { aU[jn] = z; aR[jn] = z; aXN[jn] = z; aHN[jn] = z; }

        uint4 aV[2], wV[3];
        auto load_gates = [&](int kcL) {
            const int k0 = kcL * 64;
            const bool xp = (k0 < 512);
#pragma unroll
            for (int it = 0; it < 2; ++it) {
                int i = tid + it * 256;
                int row = i >> 3, col = (i & 7) * 8;
                uint4 v;
                if (xp) {
                    if (s == 0) {
                        if (mode == 2) v = *(const uint4*)&xt[((size_t)t * B_SZ + b0 + row) * INSZ + k0 + col];
                        else           v = ld8(xb, ((size_t)(b0 + row) * T_LEN + t) * INSZ + k0 + col, f32);
                    } else {
                        v = *(const uint4*)&xin[(size_t)(b0 + row) * INSZ + k0 + col];
                    }
                } else {
                    v = *(const uint4*)&hbin[(size_t)(b0 + row) * HD + (k0 - 512 + col)];
                }
                aV[it] = v;
            }
#pragma unroll
            for (int it = 0; it < 3; ++it) {
                int i = tid + it * 256;
                int r = i >> 3, col = (i & 7) * 8;
                int g = r >> 5, rr = r & 31;
                int wrow = g * HD + n0 + rr;
                uint4 v;
                if (mode) {
                    v = xp ? *(const uint4*)&Wxb[(size_t)widx * 1572864 + (size_t)wrow * 512 + k0 + col]
                           : *(const uint4*)&Whb[(size_t)widx * 3145728 + (size_t)wrow * 1024 + (k0 - 512) + col];
                } else {
                    v = xp ? ld8(Wx, WxO + (size_t)wrow * 512 + k0 + col, f32)
                           : ld8(Wh, WhO + (size_t)wrow * 1024 + (k0 - 512) + col, f32);
                }
                wV[it] = v;
            }
        };

        load_gates(0);
        for (int kc = 0; kc < 24; ++kc) {
            const bool xp = (kc < 8);
            u16* __restrict__ axb = Ax + (kc & 1) * (64 * 72);
            u16* __restrict__ bwb = Bw + (kc & 1) * (96 * 72);
            // write phase: prefetched regs -> LDS buf[kc&1]
#pragma unroll
            for (int it = 0; it < 2; ++it) {
                int i = tid + it * 256;
                int row = i >> 3, col = (i & 7) * 8;
                *(uint4*)&axb[row * 72 + col] = aV[it];
            }
#pragma unroll
            for (int it = 0; it < 3; ++it) {
                int i = tid + it * 256;
                int r = i >> 3, col = (i & 7) * 8;
                *(uint4*)&bwb[r * 72 + col] = wV[it];
            }
            __syncthreads();
            // issue next chunk's global loads (hide latency under MFMA phase)
            if (kc < 23) load_gates(kc + 1);
            // compute phase on buf[kc&1]: this wave owns rows w*16..w*16+15
#pragma unroll
            for (int kh = 0; kh < 2; ++kh) {
                const int kf = kh * 32 + quad * 8;
                bf16x8 a0 = *(const bf16x8*)&axb[(w * 16 + m16) * 72 + kf];
#pragma unroll
                for (int ntl = 0; ntl < 2; ++ntl) {
                    bf16x8 bu = *(const bf16x8*)&bwb[(     ntl * 16 + m16) * 72 + kf];
                    bf16x8 br = *(const bf16x8*)&bwb[(32 + ntl * 16 + m16) * 72 + kf];
                    bf16x8 bn = *(const bf16x8*)&bwb[(64 + ntl * 16 + m16) * 72 + kf];
                    aU[ntl] = __builtin_amdgcn_mfma_f32_16x16x32_bf16(a0, bu, aU[ntl], 0, 0, 0);
                    aR[ntl] = __builtin_amdgcn_mfma_f32_16x16x32_bf16(a0, br, aR[ntl], 0, 0, 0);
                    if (xp) aXN[ntl] = __builtin_amdgcn_mfma_f32_16x16x32_bf16(a0, bn, aXN[ntl], 0, 0, 0);
                    else    aHN[ntl] = __builtin_amdgcn_mfma_f32_16x16x32_bf16(a0, bn, aHN[ntl], 0, 0, 0);
                }
            }
        }

        // epilogue: gate math + in-place fp32 h RMW + bf16 h + final hds
#pragma unroll
        for (int ntl = 0; ntl < 2; ++ntl) {
            const int j = n0 + ntl * 16 + m16;
            const size_t bb = (size_t)widx * 3072;
            const float bxu = ldf(bx, bb + j, f32),        bhu = ldf(bh, bb + j, f32);
            const float bxr = ldf(bx, bb + 1024 + j, f32), bhr = ldf(bh, bb + 1024 + j, f32);
            const float bxn = ldf(bx, bb + 2048 + j, f32), bhn = ldf(bh, bb + 2048 + j, f32);
#pragma unroll
            for (int q = 0; q < 4; ++q) {
                const int brow = b0 + w * 16 + quad * 4 + q;
                float su = aU[ntl][q] + bxu + bhu;
                float sr = aR[ntl][q] + bxr + bhr;
                float ug = 1.f / (1.f + __expf(-su));
                float rg = 1.f / (1.f + __expf(-sr));
                float ng = tanhf((aXN[ntl][q] + bxn) + rg * (aHN[ntl][q] + bhn));
                float hold = hfs[(size_t)brow * HD + j];
                float hnew = ug * hold + (1.f - ug) * ng;
                hfs[(size_t)brow * HD + j] = hnew;
                u16 hb = f2b(hnew);
                hbout[(size_t)brow * HD + j] = hb;
                if (t == T_LEN - 1) {
                    size_t off = PRED_N + (size_t)brow * 4096 + s * 1024 + j;
                    if (f32) ((float*)dout)[off] = hnew;
                    else     ((u16*)dout)[off]   = hb;
                }
            }
        }
    } else {
        // ---------- out role: 64 rows x 32 cols ----------
        const int ob = bid - 512;
        const int s = ob >> 6, r6 = ob & 63, mt = r6 >> 4, nt = r6 & 15;
        const int t = p - 1 - 2 * s;
        if (t < 0 || t >= T_LEN) return;
        const int widx = (s == 3) ? 2 : s;
        const int b0 = mt * 64, n0 = nt * 32;

        const u16* __restrict__ hbn = hbf + (size_t)(t & 1) * HPAR + (size_t)s * (B_SZ * HD);
        const u16* __restrict__ xin = xq + (size_t)(t & 3) * XSLOT + (size_t)s * (B_SZ * INSZ);
        u16* __restrict__ xout      = xq + (size_t)(t & 3) * XSLOT + (size_t)(s + 1) * (B_SZ * INSZ);
        const size_t WoO = (size_t)widx * 512 * 1536;

        f32x4 acc[2];
        const f32x4 z = {0.f, 0.f, 0.f, 0.f};
        acc[0] = z; acc[1] = z;

        uint4 aV[2], wV;
        auto load_out = [&](int kcL) {
            const int k0 = kcL * 64;
            const bool xp = (k0 < 512);
#pragma unroll
            for (int it = 0; it < 2; ++it) {
                int i = tid + it * 256;
                int row = i >> 3, col = (i & 7) * 8;
                uint4 v;
                if (xp) {
                    if (s == 0) {
                        if (mode == 2) v = *(const uint4*)&xt[((size_t)t * B_SZ + b0 + row) * INSZ + k0 + col];
                        else           v = ld8(xb, ((size_t)(b0 + row) * T_LEN + t) * INSZ + k0 + col, f32);
                    } else {
                        v = *(const uint4*)&xin[(size_t)(b0 + row) * INSZ + k0 + col];
                    }
                } else {
                    v = *(const uint4*)&hbn[(size_t)(b0 + row) * HD + (k0 - 512 + col)];
                }
                aV[it] = v;
            }
            {
                int r = tid >> 3, col = (tid & 7) * 8;
                if (mode) wV = *(const uint4*)&Wob[(size_t)widx * 786432 + (size_t)(n0 + r) * 1536 + k0 + col];
                else      wV = ld8(Wo, WoO + (size_t)(n0 + r) * 1536 + k0 + col, f32);
            }
        };

        load_out(0);
        for (int kc = 0; kc < 24; ++kc) {
            u16* __restrict__ axb = Ax + (kc & 1) * (64 * 72);
            u16* __restrict__ bwb = Bw + (kc & 1) * (96 * 72);
#pragma unroll
            for (int it = 0; it < 2; ++it) {
                int i = tid + it * 256;
                int row = i >> 3, col = (i & 7) * 8;
                *(uint4*)&axb[row * 72 + col] = aV[it];
            }
            {
                int r = tid >> 3, col = (tid & 7) * 8;
                *(uint4*)&bwb[r * 72 + col] = wV;
            }
            __syncthreads();
            if (kc < 23) load_out(kc + 1);
#pragma unroll
            for (int kh = 0; kh < 2; ++kh) {
                const int kf = kh * 32 + quad * 8;
                bf16x8 a0 = *(const bf16x8*)&axb[(w * 16 + m16) * 72 + kf];
#pragma unroll
                for (int ntl = 0; ntl < 2; ++ntl) {
                    bf16x8 bf = *(const bf16x8*)&bwb[(ntl * 16 + m16) * 72 + kf];
                    acc[ntl] = __builtin_amdgcn_mfma_f32_16x16x32_bf16(a0, bf, acc[ntl], 0, 0, 0);
                }
            }
        }

#pragma unroll
        for (int ntl = 0; ntl < 2; ++ntl) {
            const int j = n0 + ntl * 16 + m16;
            const float bov = ldf(bo, (size_t)widx * 512 + j, f32);
#pragma unroll
            for (int q = 0; q < 4; ++q) {
                const int brow = b0 + w * 16 + quad * 4 + q;
                float o = acc[ntl][q] + bov;
                if (s < 3) {
                    xout[(size_t)brow * INSZ + j] = f2b(o);
                } else {
                    size_t off = ((size_t)brow * T_LEN + t) * INSZ + j;
                    if (f32) ((float*)dout)[off] = o;
                    else     ((u16*)dout)[off]   = f2b(o);
                }
            }
        }
    }
}

// ---------------- batched log_softmax over 512-wide rows, in place ----------------
__global__ __launch_bounds__(256)
void sgru_lsm(void* __restrict__ preds, const int* flag)
{
    const int f32 = *flag;
    const int w = threadIdx.x >> 6, l = threadIdx.x & 63;
    const size_t row = (size_t)blockIdx.x * 4 + w;
    float x[8];
    if (f32) {
        float* p = (float*)preds + row * 512 + (size_t)l * 8;
        float4 a = *(const float4*)p, b = *(const float4*)(p + 4);
        x[0]=a.x; x[1]=a.y; x[2]=a.z; x[3]=a.w; x[4]=b.x; x[5]=b.y; x[6]=b.z; x[7]=b.w;
    } else {
        const u16* p = (const u16*)preds + row * 512 + (size_t)l * 8;
        uint4 v = *(const uint4*)p;
        const u16* pv = (const u16*)&v;
#pragma unroll
        for (int i = 0; i < 8; ++i) x[i] = b2f(pv[i]);
    }
    float m = x[0];
#pragma unroll
    for (int i = 1; i < 8; ++i) m = fmaxf(m, x[i]);
#pragma unroll
    for (int off = 32; off >= 1; off >>= 1) m = fmaxf(m, __shfl_xor(m, off, 64));
    float sum = 0.f;
#pragma unroll
    for (int i = 0; i < 8; ++i) sum += __expf(x[i] - m);
#pragma unroll
    for (int off = 32; off >= 1; off >>= 1) sum += __shfl_xor(sum, off, 64);
    const float ls = m + logf(sum);
    if (f32) {
        float* p = (float*)preds + row * 512 + (size_t)l * 8;
        float4 a, b;
        a.x=x[0]-ls; a.y=x[1]-ls; a.z=x[2]-ls; a.w=x[3]-ls;
        b.x=x[4]-ls; b.y=x[5]-ls; b.z=x[6]-ls; b.w=x[7]-ls;
        *(float4*)p = a; *(float4*)(p + 4) = b;
    } else {
        u16* p = (u16*)preds + row * 512 + (size_t)l * 8;
        union { u16 o[8]; uint4 v; } u;
#pragma unroll
        for (int i = 0; i < 8; ++i) u.o[i] = f2b(x[i] - ls);
        *(uint4*)p = u.v;
    }
}

extern "C" void kernel_launch(void* const* d_in, const int* in_sizes, int n_in,
                              void* d_out, int out_size, void* d_ws, size_t ws_size,
                              hipStream_t stream) {
    const void* xb = d_in[0];
    const void* h0 = d_in[1];
    const void* Wx = d_in[2];
    const void* bx = d_in[3];
    const void* Wh = d_in[4];
    const void* bh = d_in[5];
    const void* Wo = d_in[6];
    const void* bo = d_in[7];
    (void)in_sizes; (void)n_in; (void)out_size;

    char* ws = (char*)d_ws;
    float* hf  = (float*)(ws + OFF_HF);     // [4][256][1024] f32, in-place (4 MB)
    u16*   hbf = (u16*)(ws + OFF_HBF);      // [2][4][256][1024] bf16 (4 MB)
    u16*   xq  = (u16*)(ws + OFF_XQ);       // [4][4][256][512]  bf16 (4 MB)
    int*   flag = (int*)(ws + OFF_FLAG);    // dtype flag
    u16*   Wxb = (u16*)(ws + OFF_WXB);      // [3][3072][512]  bf16
    u16*   Whb = (u16*)(ws + OFF_WHB);      // [3][3072][1024] bf16
    u16*   Wob = (u16*)(ws + OFF_WOB);      // [3][512][1536]  bf16
    u16*   xt  = (u16*)(ws + OFF_XT);       // [256][256][512] bf16, time-major

    const int mode = (ws_size >= WS_NEED_X) ? 2 : (ws_size >= WS_NEED_W ? 1 : 0);

    sgru_probe<<<1, 64, 0, stream>>>(Wx, flag);
    sgru_init<<<4096, 256, 0, stream>>>(h0, hf, hbf, xq, flag);
    if (mode >= 1) {
        sgru_cvt<<<2304, 256, 0, stream>>>(Wx, Wxb, flag);  // 4,718,592 elems
        sgru_cvt<<<4608, 256, 0, stream>>>(Wh, Whb, flag);  // 9,437,184 elems
        sgru_cvt<<<1152, 256, 0, stream>>>(Wo, Wob, flag);  // 2,359,296 elems
    }
    if (mode == 2) {
        sgru_cvtx<<<16384, 256, 0, stream>>>(xb, xt, flag); // 33,554,432 elems
    }
    for (int p = 0; p < T_LEN + 7; ++p) {   // 263 steps: last out at p = 255 + 1 + 6
        sgru_step<<<768, 256, 0, stream>>>(p, xb, Wx, bx, Wh, bh, Wo, bo,
                                           hf, hbf, xq, d_out, flag,
                                           Wxb, Whb, Wob, xt, mode);
    }
    sgru_lsm<<<16384, 256, 0, stream>>>(d_out, flag);
}